// Round 1
// baseline (10931.452 us; speedup 1.0000x reference)
//
#include <hip/hip_runtime.h>

#define N0C 200000
#define N1C 600000
#define N2C 400000
#define NGC 128
#define D 32

// out[n, 32] = x[n, :din] @ W[din, 32]; one thread per (row, j)
__global__ void xw_kernel(const float* __restrict__ x, const float* __restrict__ W,
                          float* __restrict__ out, int n, int din) {
    __shared__ float Ws[64 * D];
    int nw = din * D;
    for (int i = threadIdx.x; i < nw; i += blockDim.x) Ws[i] = W[i];
    __syncthreads();
    int t = blockIdx.x * blockDim.x + threadIdx.x;
    int row = t >> 5;
    int j = t & 31;
    if (row >= n) return;
    const float* xr = x + (size_t)row * din;
    float s = 0.f;
#pragma unroll 8
    for (int k = 0; k < din; ++k) s = fmaf(xr[k], Ws[k * D + j], s);
    out[(size_t)row * D + j] = s;
}

// acc[rows[e], j] += vals[e] * XW[cols[e], j]; 32 lanes per edge
__global__ void spmm_kernel(const int* __restrict__ rows, const int* __restrict__ cols,
                            const float* __restrict__ vals, const float* __restrict__ XW,
                            float* __restrict__ acc, int nnz) {
    long long t = (long long)blockIdx.x * blockDim.x + threadIdx.x;
    int e = (int)(t >> 5);
    int j = (int)(t & 31);
    if (e >= nnz) return;
    int r = rows[e];
    int c = cols[e];
    float v = vals[e];
    atomicAdd(&acc[(size_t)r * D + j], v * XW[(size_t)c * D + j]);
}

__global__ void relu_scale_kernel(float* __restrict__ buf, float scale, int n4) {
    int t = blockIdx.x * blockDim.x + threadIdx.x;
    if (t >= n4) return;
    float4 v = reinterpret_cast<float4*>(buf)[t];
    v.x = fmaxf(v.x, 0.f) * scale;
    v.y = fmaxf(v.y, 0.f) * scale;
    v.z = fmaxf(v.z, 0.f) * scale;
    v.w = fmaxf(v.w, 0.f) * scale;
    reinterpret_cast<float4*>(buf)[t] = v;
}

// segment mean-pool numerator/denominator: batch is sorted, so run-accumulate
__global__ void pool_kernel(const float* __restrict__ x1, const int* __restrict__ batch,
                            float* __restrict__ sums, float* __restrict__ cnt, int n) {
    const int RPG = 512;  // rows per 32-lane group
    int j = threadIdx.x & 31;
    int s = threadIdx.x >> 5;
    long long start = ((long long)blockIdx.x * 8 + s) * RPG;
    if (start >= n) return;
    long long end = start + RPG;
    if (end > n) end = n;
    int curg = batch[start];
    float a = 0.f, c = 0.f;
    for (long long r = start; r < end; ++r) {
        int g = batch[r];
        if (g != curg) {
            atomicAdd(&sums[(size_t)curg * D + j], a);
            if (j == 0) atomicAdd(&cnt[curg], c);
            a = 0.f; c = 0.f; curg = g;
        }
        a += fabsf(x1[(size_t)r * D + j]);
        c += 1.f;
    }
    atomicAdd(&sums[(size_t)curg * D + j], a);
    if (j == 0) atomicAdd(&cnt[curg], c);
}

// pooled -> mlp1(relu) -> mlp2 -> softmax; 1 thread per graph
__global__ void head_kernel(const float* __restrict__ sums, const float* __restrict__ cnt,
                            const float* __restrict__ w1, const float* __restrict__ b1,
                            const float* __restrict__ w2, const float* __restrict__ b2,
                            float* __restrict__ out) {
    __shared__ float W1s[D * D], W2s[D * 10], B1s[D], B2s[10];
    int tid = threadIdx.x;
    for (int i = tid; i < D * D; i += blockDim.x) W1s[i] = w1[i];
    for (int i = tid; i < D * 10; i += blockDim.x) W2s[i] = w2[i];
    if (tid < D) B1s[tid] = b1[tid];
    if (tid < 10) B2s[tid] = b2[tid];
    __syncthreads();
    int g = tid;
    if (g >= NGC) return;
    float invc = 1.f / fmaxf(cnt[g], 1.f);
    float p[D];
#pragma unroll
    for (int k = 0; k < D; ++k) p[k] = sums[(size_t)g * D + k] * invc;
    float h[D];
#pragma unroll
    for (int j = 0; j < D; ++j) {
        float s = B1s[j];
#pragma unroll
        for (int k = 0; k < D; ++k) s = fmaf(p[k], W1s[k * D + j], s);
        h[j] = fmaxf(s, 0.f);
    }
    float l[10];
    float m = -1e30f;
#pragma unroll
    for (int o = 0; o < 10; ++o) {
        float s = B2s[o];
#pragma unroll
        for (int k = 0; k < D; ++k) s = fmaf(h[k], W2s[k * 10 + o], s);
        l[o] = s;
        m = fmaxf(m, s);
    }
    float den = 0.f;
#pragma unroll
    for (int o = 0; o < 10; ++o) { l[o] = expf(l[o] - m); den += l[o]; }
    float inv = 1.f / den;
#pragma unroll
    for (int o = 0; o < 10; ++o) out[g * 10 + o] = l[o] * inv;
}

extern "C" void kernel_launch(void* const* d_in, const int* in_sizes, int n_in,
                              void* d_out, int out_size, void* d_ws, size_t ws_size,
                              hipStream_t stream) {
    const float* X0 = (const float*)d_in[0];
    const float* X1 = (const float*)d_in[1];
    const float* X2 = (const float*)d_in[2];
    // sparse matrices in input order: 0=L0,1=L1,2=L2,3=B2D3,4=D2B1TD1inv,5=D1invB1,6=B2TD2inv
    const int* spr[7]; const int* spc[7]; const float* spv[7]; int spn[7];
    for (int m = 0; m < 7; ++m) {
        spr[m] = (const int*)d_in[3 + m * 3];
        spc[m] = (const int*)d_in[4 + m * 3];
        spv[m] = (const float*)d_in[5 + m * 3];
        spn[m] = in_sizes[3 + m * 3];
    }
    const int* batch1 = (const int*)d_in[24];
    const float* W1 = (const float*)d_in[25];
    const float* W234 = (const float*)d_in[26];
    const float* mlp1_w = (const float*)d_in[27];
    const float* mlp1_b = (const float*)d_in[28];
    const float* mlp2_w = (const float*)d_in[29];
    const float* mlp2_b = (const float*)d_in[30];
    float* out = (float*)d_out;

    const size_t NT = (size_t)(N0C + N1C + N2C) * D;  // 38.4M floats
    float* P = (float*)d_ws;
    float* Q = P + NT;
    float* XW = Q + NT;                     // N1C*D scratch (largest src)
    float* sums = XW + (size_t)N1C * D;     // [128,32]
    float* cnt = sums + (size_t)NGC * D;    // [128]

    const size_t off0 = 0;
    const size_t off1 = (size_t)N0C * D;
    const size_t off2 = (size_t)(N0C + N1C) * D;

    float* cur = P;
    float* nxt = Q;

    for (int l = 0; l < 4; ++l) {
        const int din = (l == 0) ? 64 : 32;
        const float* x0s = (l == 0) ? X0 : cur + off0;
        const float* x1s = (l == 0) ? X1 : cur + off1;
        const float* x2s = (l == 0) ? X2 : cur + off2;
        const float* Wb = (l == 0) ? W1 : W234 + (size_t)(l - 1) * 7 * 32 * 32;
        const size_t wstride = (size_t)din * 32;

        hipMemsetAsync(nxt, 0, NT * sizeof(float), stream);

        // {src, nsrc, W index, sparse-mat index, dst offset}
        struct Combo { const float* src; int nsrc; int wk; int mat; size_t dst; };
        const Combo combos[7] = {
            { x0s, N0C, 0, 0, off0 },  // n2n: L0 @ (x0 W0)          -> acc0
            { x0s, N0C, 1, 4, off1 },  // n2e: D2B1TD1inv @ (x0 W1)  -> acc1
            { x1s, N1C, 2, 1, off1 },  // e2e: L1 @ (x1 W2)          -> acc1
            { x1s, N1C, 3, 5, off0 },  // e2n: D1invB1 @ (x1 W3)     -> acc0
            { x1s, N1C, 4, 6, off2 },  // e2t: B2TD2inv @ (x1 W4)    -> acc2
            { x2s, N2C, 5, 3, off1 },  // t2e: B2D3 @ (x2 W5)        -> acc1
            { x2s, N2C, 6, 2, off2 },  // t2t: L2 @ (x2 W6)          -> acc2
        };
        for (int ci = 0; ci < 7; ++ci) {
            const Combo& cb = combos[ci];
            int gx = (int)(((size_t)cb.nsrc * D + 255) / 256);
            xw_kernel<<<gx, 256, 0, stream>>>(cb.src, Wb + (size_t)cb.wk * wstride,
                                              XW, cb.nsrc, din);
            int m = cb.mat;
            int ge = (int)(((size_t)spn[m] * D + 255) / 256);
            spmm_kernel<<<ge, 256, 0, stream>>>(spr[m], spc[m], spv[m], XW,
                                                nxt + cb.dst, spn[m]);
        }

        relu_scale_kernel<<<(N0C * D / 4 + 255) / 256, 256, 0, stream>>>(
            nxt + off0, 0.5f, N0C * D / 4);
        relu_scale_kernel<<<(N1C * D / 4 + 255) / 256, 256, 0, stream>>>(
            nxt + off1, 1.0f / 3.0f, N1C * D / 4);
        relu_scale_kernel<<<(N2C * D / 4 + 255) / 256, 256, 0, stream>>>(
            nxt + off2, 0.5f, N2C * D / 4);

        float* tmp = cur; cur = nxt; nxt = tmp;
    }

    hipMemsetAsync(sums, 0, (size_t)(NGC * D + NGC) * sizeof(float), stream);
    {
        int groups = (N1C + 511) / 512;
        int blocks = (groups + 7) / 8;
        pool_kernel<<<blocks, 256, 0, stream>>>(cur + off1, batch1, sums, cnt, N1C);
    }
    head_kernel<<<1, 128, 0, stream>>>(sums, cnt, mlp1_w, mlp1_b, mlp2_w, mlp2_b, out);
}

// Round 2
// 9614.750 us; speedup vs baseline: 1.1369x; 1.1369x over previous
//
#include <hip/hip_runtime.h>

#define N0C 200000
#define N1C 600000
#define N2C 400000
#define NGC 128
#define D 32
#define SCAN_TILE 2048  // 256 threads * 8 elements

// ---------- dense projection: out[n,32] = x[n,:din] @ W[din,32] ----------
__global__ void xw_kernel(const float* __restrict__ x, const float* __restrict__ W,
                          float* __restrict__ out, int n, int din) {
    __shared__ float Ws[64 * D];
    int nw = din * D;
    for (int i = threadIdx.x; i < nw; i += blockDim.x) Ws[i] = W[i];
    __syncthreads();
    int t = blockIdx.x * blockDim.x + threadIdx.x;
    int row = t >> 5;
    int j = t & 31;
    if (row >= n) return;
    const float* xr = x + (size_t)row * din;
    float s = 0.f;
#pragma unroll 8
    for (int k = 0; k < din; ++k) s = fmaf(xr[k], Ws[k * D + j], s);
    out[(size_t)row * D + j] = s;
}

// ---------- CSR build ----------
__global__ void hist_kernel(const int* __restrict__ rows, int* __restrict__ counts, int nnz) {
    int e = blockIdx.x * blockDim.x + threadIdx.x;
    if (e >= nnz) return;
    atomicAdd(&counts[rows[e]], 1);
}

__global__ void scan_phase1(const int* __restrict__ counts, int* __restrict__ bsums, int n) {
    __shared__ int sd[256];
    int base = blockIdx.x * SCAN_TILE;
    int s = 0;
    for (int i = threadIdx.x; i < SCAN_TILE; i += 256) {
        int idx = base + i;
        s += (idx < n) ? counts[idx] : 0;
    }
    sd[threadIdx.x] = s;
    __syncthreads();
    for (int o = 128; o > 0; o >>= 1) {
        if (threadIdx.x < o) sd[threadIdx.x] += sd[threadIdx.x + o];
        __syncthreads();
    }
    if (threadIdx.x == 0) bsums[blockIdx.x] = sd[0];
}

__global__ void scan_phase2(int* __restrict__ bsums, int nb) {
    __shared__ int sd[1024];
    for (int i = threadIdx.x; i < nb; i += 256) sd[i] = bsums[i];
    __syncthreads();
    if (threadIdx.x == 0) {
        int acc = 0;
        for (int i = 0; i < nb; ++i) { int v = sd[i]; sd[i] = acc; acc += v; }
        bsums[nb] = acc;  // total
    }
    __syncthreads();
    for (int i = threadIdx.x; i < nb; i += 256) bsums[i] = sd[i];
}

__global__ void scan_phase3(const int* __restrict__ counts, const int* __restrict__ bsums,
                            int* __restrict__ rowptr, int n) {
    __shared__ int sd[256];
    int base = blockIdx.x * SCAN_TILE + threadIdx.x * 8;
    int v[8];
    int s = 0;
#pragma unroll
    for (int u = 0; u < 8; ++u) {
        int idx = base + u;
        int c = (idx < n) ? counts[idx] : 0;
        v[u] = s;
        s += c;
    }
    sd[threadIdx.x] = s;
    __syncthreads();
    if (threadIdx.x == 0) {
        int acc = bsums[blockIdx.x];
        for (int i = 0; i < 256; ++i) { int q = sd[i]; sd[i] = acc; acc += q; }
    }
    __syncthreads();
    int off = sd[threadIdx.x];
#pragma unroll
    for (int u = 0; u < 8; ++u) {
        int idx = base + u;
        if (idx < n) rowptr[idx] = off + v[u];
    }
}

__global__ void set_total_kernel(int* __restrict__ dst, const int* __restrict__ src) {
    *dst = *src;
}

__global__ void scatter_kernel(const int* __restrict__ rows, const int* __restrict__ cols,
                               const float* __restrict__ vals, int* __restrict__ cursor,
                               int2* __restrict__ cv, int nnz) {
    int e = blockIdx.x * blockDim.x + threadIdx.x;
    if (e >= nnz) return;
    int r = rows[e];
    int pos = atomicAdd(&cursor[r], 1);
    cv[pos] = make_int2(cols[e], __float_as_int(vals[e]));
}

// ---------- fused per-rank CSR spmm (up to 3 mats) + relu + scale ----------
__global__ void csr_rank_kernel(const int* __restrict__ rp0, const int2* __restrict__ cv0,
                                const float* __restrict__ xw0,
                                const int* __restrict__ rp1, const int2* __restrict__ cv1,
                                const float* __restrict__ xw1,
                                const int* __restrict__ rp2, const int2* __restrict__ cv2,
                                const float* __restrict__ xw2,
                                float* __restrict__ out, float scale, int n) {
    int t = blockIdx.x * blockDim.x + threadIdx.x;
    int row = t >> 5;
    int j = t & 31;
    if (row >= n) return;
    float s = 0.f;
    {
        int k0 = rp0[row], k1 = rp0[row + 1];
        for (int k = k0; k < k1; ++k) {
            int2 p = cv0[k];
            s = fmaf(__int_as_float(p.y), xw0[(size_t)p.x * D + j], s);
        }
    }
    if (rp1) {
        int k0 = rp1[row], k1 = rp1[row + 1];
        for (int k = k0; k < k1; ++k) {
            int2 p = cv1[k];
            s = fmaf(__int_as_float(p.y), xw1[(size_t)p.x * D + j], s);
        }
    }
    if (rp2) {
        int k0 = rp2[row], k1 = rp2[row + 1];
        for (int k = k0; k < k1; ++k) {
            int2 p = cv2[k];
            s = fmaf(__int_as_float(p.y), xw2[(size_t)p.x * D + j], s);
        }
    }
    out[(size_t)row * D + j] = fmaxf(s, 0.f) * scale;
}

// ---------- pooling (batch sorted) ----------
__global__ void pool_kernel(const float* __restrict__ x1, const int* __restrict__ batch,
                            float* __restrict__ sums, float* __restrict__ cnt, int n) {
    const int RPG = 512;
    int j = threadIdx.x & 31;
    int s = threadIdx.x >> 5;
    long long start = ((long long)blockIdx.x * 8 + s) * RPG;
    if (start >= n) return;
    long long end = start + RPG;
    if (end > n) end = n;
    int curg = batch[start];
    float a = 0.f, c = 0.f;
    for (long long r = start; r < end; ++r) {
        int g = batch[r];
        if (g != curg) {
            atomicAdd(&sums[(size_t)curg * D + j], a);
            if (j == 0) atomicAdd(&cnt[curg], c);
            a = 0.f; c = 0.f; curg = g;
        }
        a += fabsf(x1[(size_t)r * D + j]);
        c += 1.f;
    }
    atomicAdd(&sums[(size_t)curg * D + j], a);
    if (j == 0) atomicAdd(&cnt[curg], c);
}

// ---------- head ----------
__global__ void head_kernel(const float* __restrict__ sums, const float* __restrict__ cnt,
                            const float* __restrict__ w1, const float* __restrict__ b1,
                            const float* __restrict__ w2, const float* __restrict__ b2,
                            float* __restrict__ out) {
    __shared__ float W1s[D * D], W2s[D * 10], B1s[D], B2s[10];
    int tid = threadIdx.x;
    for (int i = tid; i < D * D; i += blockDim.x) W1s[i] = w1[i];
    for (int i = tid; i < D * 10; i += blockDim.x) W2s[i] = w2[i];
    if (tid < D) B1s[tid] = b1[tid];
    if (tid < 10) B2s[tid] = b2[tid];
    __syncthreads();
    int g = tid;
    if (g >= NGC) return;
    float invc = 1.f / fmaxf(cnt[g], 1.f);
    float p[D];
#pragma unroll
    for (int k = 0; k < D; ++k) p[k] = sums[(size_t)g * D + k] * invc;
    float h[D];
#pragma unroll
    for (int j = 0; j < D; ++j) {
        float s = B1s[j];
#pragma unroll
        for (int k = 0; k < D; ++k) s = fmaf(p[k], W1s[k * D + j], s);
        h[j] = fmaxf(s, 0.f);
    }
    float l[10];
    float m = -1e30f;
#pragma unroll
    for (int o = 0; o < 10; ++o) {
        float s = B2s[o];
#pragma unroll
        for (int k = 0; k < D; ++k) s = fmaf(h[k], W2s[k * 10 + o], s);
        l[o] = s;
        m = fmaxf(m, s);
    }
    float den = 0.f;
#pragma unroll
    for (int o = 0; o < 10; ++o) { l[o] = expf(l[o] - m); den += l[o]; }
    float inv = 1.f / den;
#pragma unroll
    for (int o = 0; o < 10; ++o) out[g * 10 + o] = l[o] * inv;
}

extern "C" void kernel_launch(void* const* d_in, const int* in_sizes, int n_in,
                              void* d_out, int out_size, void* d_ws, size_t ws_size,
                              hipStream_t stream) {
    const float* X0 = (const float*)d_in[0];
    const float* X1 = (const float*)d_in[1];
    const float* X2 = (const float*)d_in[2];
    // mats: 0=L0,1=L1,2=L2,3=B2D3,4=D2B1TD1inv,5=D1invB1,6=B2TD2inv
    const int* spr[7]; const int* spc[7]; const float* spv[7]; int spn[7];
    for (int m = 0; m < 7; ++m) {
        spr[m] = (const int*)d_in[3 + m * 3];
        spc[m] = (const int*)d_in[4 + m * 3];
        spv[m] = (const float*)d_in[5 + m * 3];
        spn[m] = in_sizes[3 + m * 3];
    }
    const int* batch1 = (const int*)d_in[24];
    const float* W1 = (const float*)d_in[25];
    const float* W234 = (const float*)d_in[26];
    const float* mlp1_w = (const float*)d_in[27];
    const float* mlp1_b = (const float*)d_in[28];
    const float* mlp2_w = (const float*)d_in[29];
    const float* mlp2_b = (const float*)d_in[30];
    float* out = (float*)d_out;

    const int nrows_mat[7] = { N0C, N1C, N2C, N1C, N1C, N0C, N2C };

    // ---- workspace carve ----
    const size_t NT = (size_t)(N0C + N1C + N2C) * D;  // 38.4M floats
    float* P = (float*)d_ws;
    float* Q = P + NT;
    float* XW = Q + NT;                         // 1.2M rows * 32 = 38.4M floats
    float* fend = XW + NT;
    int2* cv_base = (int2*)fend;                // total nnz int2
    size_t total_nnz = 0;
    for (int m = 0; m < 7; ++m) total_nnz += (size_t)spn[m];
    int* rowptr_base = (int*)(cv_base + total_nnz);
    size_t total_rp = 0;
    for (int m = 0; m < 7; ++m) total_rp += (size_t)nrows_mat[m] + 1;
    int* tmp = rowptr_base + total_rp;          // counts / cursor, max 600k
    int* bsums = tmp + N1C;                     // up to 1025
    float* sums = (float*)(bsums + 1040);
    float* cnt = sums + (size_t)NGC * D;

    // per-mat CSR pointers
    int* rp_m[7]; int2* cv_m[7];
    {
        size_t ro = 0, co = 0;
        for (int m = 0; m < 7; ++m) {
            rp_m[m] = rowptr_base + ro;
            cv_m[m] = cv_base + co;
            ro += (size_t)nrows_mat[m] + 1;
            co += (size_t)spn[m];
        }
    }

    // ---- build CSR (7 mats, reused by all 4 layers) ----
    for (int m = 0; m < 7; ++m) {
        int nr = nrows_mat[m];
        int nnz = spn[m];
        int nb = (nr + SCAN_TILE - 1) / SCAN_TILE;
        hipMemsetAsync(tmp, 0, (size_t)nr * sizeof(int), stream);
        hist_kernel<<<(nnz + 255) / 256, 256, 0, stream>>>(spr[m], tmp, nnz);
        scan_phase1<<<nb, 256, 0, stream>>>(tmp, bsums, nr);
        scan_phase2<<<1, 256, 0, stream>>>(bsums, nb);
        scan_phase3<<<nb, 256, 0, stream>>>(tmp, bsums, rp_m[m], nr);
        set_total_kernel<<<1, 1, 0, stream>>>(rp_m[m] + nr, bsums + nb);
        hipMemcpyAsync(tmp, rp_m[m], (size_t)nr * sizeof(int),
                       hipMemcpyDeviceToDevice, stream);
        scatter_kernel<<<(nnz + 255) / 256, 256, 0, stream>>>(
            spr[m], spc[m], spv[m], tmp, cv_m[m], nnz);
    }

    const size_t off0 = 0;
    const size_t off1 = (size_t)N0C * D;
    const size_t off2 = (size_t)(N0C + N1C) * D;

    float* cur = P;
    float* nxt = Q;

    // rank descriptors: mats + (source sel, W index) per mat
    struct RankMat { int mat; int src; int wk; int nsrc; };
    struct Rank { int nmats; RankMat m[3]; int nout; float scale; size_t dst; };
    const Rank ranks[3] = {
        { 2, { {0, 0, 0, N0C}, {5, 1, 3, N1C}, {0,0,0,0} }, N0C, 0.5f, off0 },
        { 3, { {4, 0, 1, N0C}, {1, 1, 2, N1C}, {3, 2, 5, N2C} }, N1C, 1.f / 3.f, off1 },
        { 2, { {6, 1, 4, N1C}, {2, 2, 6, N2C}, {0,0,0,0} }, N2C, 0.5f, off2 },
    };

    for (int l = 0; l < 4; ++l) {
        const int din = (l == 0) ? 64 : 32;
        const float* xs[3] = {
            (l == 0) ? X0 : cur + off0,
            (l == 0) ? X1 : cur + off1,
            (l == 0) ? X2 : cur + off2,
        };
        const float* Wb = (l == 0) ? W1 : W234 + (size_t)(l - 1) * 7 * 32 * 32;
        const size_t wstride = (size_t)din * 32;

        for (int r = 0; r < 3; ++r) {
            const Rank& rk = ranks[r];
            // stage XW for this rank's mats
            float* xw_ptr[3] = { nullptr, nullptr, nullptr };
            size_t xo = 0;
            for (int i = 0; i < rk.nmats; ++i) {
                const RankMat& rm = rk.m[i];
                xw_ptr[i] = XW + xo;
                int gx = (int)(((size_t)rm.nsrc * D + 255) / 256);
                xw_kernel<<<gx, 256, 0, stream>>>(xs[rm.src], Wb + (size_t)rm.wk * wstride,
                                                  xw_ptr[i], rm.nsrc, din);
                xo += (size_t)rm.nsrc * D;
            }
            int gb = (int)(((size_t)rk.nout * 32 + 255) / 256);
            csr_rank_kernel<<<gb, 256, 0, stream>>>(
                rp_m[rk.m[0].mat], cv_m[rk.m[0].mat], xw_ptr[0],
                rk.nmats > 1 ? rp_m[rk.m[1].mat] : nullptr,
                rk.nmats > 1 ? cv_m[rk.m[1].mat] : nullptr, xw_ptr[1],
                rk.nmats > 2 ? rp_m[rk.m[2].mat] : nullptr,
                rk.nmats > 2 ? cv_m[rk.m[2].mat] : nullptr, xw_ptr[2],
                nxt + rk.dst, rk.scale, rk.nout);
        }

        float* t2 = cur; cur = nxt; nxt = t2;
    }

    hipMemsetAsync(sums, 0, (size_t)(NGC * D + NGC) * sizeof(float), stream);
    {
        int groups = (N1C + 511) / 512;
        int blocks = (groups + 7) / 8;
        pool_kernel<<<blocks, 256, 0, stream>>>(cur + off1, batch1, sums, cnt, N1C);
    }
    head_kernel<<<1, 128, 0, stream>>>(sums, cnt, mlp1_w, mlp1_b, mlp2_w, mlp2_b, out);
}

// Round 3
// 7736.905 us; speedup vs baseline: 1.4129x; 1.2427x over previous
//
#include <hip/hip_runtime.h>
#include <hip/hip_fp16.h>

#define N0C 200000
#define N1C 600000
#define N2C 400000
#define NRC (N0C + N1C + N2C)
#define RB0 0
#define RB1 N0C
#define RB2 (N0C + N1C)
#define NGC 128
#define D 32
#define SCAN_TILE 2048

// ---------- input fp32 -> fp16 ----------
__global__ void tohalf_kernel(const float* __restrict__ x, __half* __restrict__ o, size_t n4) {
    size_t t = (size_t)blockIdx.x * blockDim.x + threadIdx.x;
    size_t stride = (size_t)gridDim.x * blockDim.x;
    for (size_t i = t; i < n4; i += stride) {
        float4 v = reinterpret_cast<const float4*>(x)[i];
        __half2 h01 = __floats2half2_rn(v.x, v.y);
        __half2 h23 = __floats2half2_rn(v.z, v.w);
        reinterpret_cast<__half2*>(o)[2 * i] = h01;
        reinterpret_cast<__half2*>(o)[2 * i + 1] = h23;
    }
}

// ---------- CSR build ----------
__global__ void hist_kernel(const int* __restrict__ rows, int* __restrict__ counts, int nnz) {
    int e = blockIdx.x * blockDim.x + threadIdx.x;
    if (e >= nnz) return;
    atomicAdd(&counts[rows[e]], 1);
}

__global__ void scan_phase1(const int* __restrict__ counts, int* __restrict__ bsums, int n) {
    __shared__ int sd[256];
    int base = blockIdx.x * SCAN_TILE;
    int s = 0;
    for (int i = threadIdx.x; i < SCAN_TILE; i += 256) {
        int idx = base + i;
        s += (idx < n) ? counts[idx] : 0;
    }
    sd[threadIdx.x] = s;
    __syncthreads();
    for (int o = 128; o > 0; o >>= 1) {
        if (threadIdx.x < o) sd[threadIdx.x] += sd[threadIdx.x + o];
        __syncthreads();
    }
    if (threadIdx.x == 0) bsums[blockIdx.x] = sd[0];
}

__global__ void scan_phase2(int* __restrict__ bsums, int nb) {
    __shared__ int sd[1024];
    for (int i = threadIdx.x; i < nb; i += 256) sd[i] = bsums[i];
    __syncthreads();
    if (threadIdx.x == 0) {
        int acc = 0;
        for (int i = 0; i < nb; ++i) { int v = sd[i]; sd[i] = acc; acc += v; }
        bsums[nb] = acc;
    }
    __syncthreads();
    for (int i = threadIdx.x; i < nb; i += 256) bsums[i] = sd[i];
}

__global__ void scan_phase3(const int* __restrict__ counts, const int* __restrict__ bsums,
                            int* __restrict__ rowptr, int n) {
    __shared__ int sd[256];
    int base = blockIdx.x * SCAN_TILE + threadIdx.x * 8;
    int v[8];
    int s = 0;
#pragma unroll
    for (int u = 0; u < 8; ++u) {
        int idx = base + u;
        int c = (idx < n) ? counts[idx] : 0;
        v[u] = s;
        s += c;
    }
    sd[threadIdx.x] = s;
    __syncthreads();
    if (threadIdx.x == 0) {
        int acc = bsums[blockIdx.x];
        for (int i = 0; i < 256; ++i) { int q = sd[i]; sd[i] = acc; acc += q; }
    }
    __syncthreads();
    int off = sd[threadIdx.x];
#pragma unroll
    for (int u = 0; u < 8; ++u) {
        int idx = base + u;
        if (idx < n) rowptr[idx] = off + v[u];
    }
}

__global__ void set_total_kernel(int* __restrict__ dst, const int* __restrict__ src) {
    *dst = *src;
}

// scatter with GLOBAL column index (col + colbase into concatenated activation buffer)
__global__ void scatter_kernel(const int* __restrict__ rows, const int* __restrict__ cols,
                               const float* __restrict__ vals, int* __restrict__ cursor,
                               int2* __restrict__ cv, int nnz, int colbase) {
    int e = blockIdx.x * blockDim.x + threadIdx.x;
    if (e >= nnz) return;
    int r = rows[e];
    int pos = atomicAdd(&cursor[r], 1);
    cv[pos] = make_int2(cols[e] + colbase, __float_as_int(vals[e]));
}

// ---------- fused rank kernel: gather raw activations, W applied per-row via shfl ----------
template <int DIN, int NM>
__global__ void rank_kernel(const int* __restrict__ rp0, const int2* __restrict__ cv0,
                            const float* __restrict__ Wg0,
                            const int* __restrict__ rp1, const int2* __restrict__ cv1,
                            const float* __restrict__ Wg1,
                            const int* __restrict__ rp2, const int2* __restrict__ cv2,
                            const float* __restrict__ Wg2,
                            const __half* __restrict__ xact, __half* __restrict__ outbuf,
                            int rowbase, float scale, int n) {
    __shared__ float Ws[NM * DIN * 32];
    {
        const float* wg[3] = { Wg0, Wg1, Wg2 };
#pragma unroll
        for (int m = 0; m < NM; ++m)
            for (int i = threadIdx.x; i < DIN * 32; i += 256)
                Ws[m * DIN * 32 + i] = wg[m][i];
    }
    __syncthreads();

    int t = blockIdx.x * blockDim.x + threadIdx.x;
    int row = t >> 5;
    int j = t & 31;
    if (row >= n) return;

    float aL[NM], aH[NM];
#pragma unroll
    for (int m = 0; m < NM; ++m) { aL[m] = 0.f; aH[m] = 0.f; }

    const int* rps[3] = { rp0, rp1, rp2 };
    const int2* cvs[3] = { cv0, cv1, cv2 };

#pragma unroll
    for (int m = 0; m < NM; ++m) {
        const int* rp = rps[m];
        const int2* cv = cvs[m];
        int k0 = rp[row], k1 = rp[row + 1];
        float lo = 0.f, hi = 0.f;
        int k = k0;
        for (; k + 4 <= k1; k += 4) {
            int2 e0 = cv[k], e1 = cv[k + 1], e2 = cv[k + 2], e3 = cv[k + 3];
            const __half* p0 = xact + (size_t)e0.x * DIN;
            const __half* p1 = xact + (size_t)e1.x * DIN;
            const __half* p2 = xact + (size_t)e2.x * DIN;
            const __half* p3 = xact + (size_t)e3.x * DIN;
            float x0 = __half2float(p0[j]), x1 = __half2float(p1[j]);
            float x2 = __half2float(p2[j]), x3 = __half2float(p3[j]);
            float v0 = __int_as_float(e0.y), v1 = __int_as_float(e1.y);
            float v2 = __int_as_float(e2.y), v3 = __int_as_float(e3.y);
            lo = fmaf(v0, x0, lo); lo = fmaf(v1, x1, lo);
            lo = fmaf(v2, x2, lo); lo = fmaf(v3, x3, lo);
            if (DIN == 64) {
                float y0 = __half2float(p0[32 + j]), y1 = __half2float(p1[32 + j]);
                float y2 = __half2float(p2[32 + j]), y3 = __half2float(p3[32 + j]);
                hi = fmaf(v0, y0, hi); hi = fmaf(v1, y1, hi);
                hi = fmaf(v2, y2, hi); hi = fmaf(v3, y3, hi);
            }
        }
        for (; k < k1; ++k) {
            int2 e0 = cv[k];
            const __half* p0 = xact + (size_t)e0.x * DIN;
            float v0 = __int_as_float(e0.y);
            lo = fmaf(v0, __half2float(p0[j]), lo);
            if (DIN == 64) hi = fmaf(v0, __half2float(p0[32 + j]), hi);
        }
        aL[m] = lo; aH[m] = hi;
    }

    // s[j] = sum_m sum_k a_m[k] * W_m[k][j]
    float s = 0.f;
#pragma unroll
    for (int k = 0; k < 32; ++k) {
#pragma unroll
        for (int m = 0; m < NM; ++m)
            s = fmaf(__shfl(aL[m], k, 32), Ws[m * DIN * 32 + k * 32 + j], s);
    }
    if (DIN == 64) {
#pragma unroll
        for (int k = 0; k < 32; ++k) {
#pragma unroll
            for (int m = 0; m < NM; ++m)
                s = fmaf(__shfl(aH[m], k, 32), Ws[m * DIN * 32 + (k + 32) * 32 + j], s);
        }
    }
    outbuf[(size_t)(rowbase + row) * 32 + j] = __float2half(fmaxf(s, 0.f) * scale);
}

// ---------- pooling (batch sorted) ----------
__global__ void pool_kernel(const __half* __restrict__ x1, const int* __restrict__ batch,
                            float* __restrict__ sums, float* __restrict__ cnt, int n) {
    const int RPG = 512;
    int j = threadIdx.x & 31;
    int s = threadIdx.x >> 5;
    long long start = ((long long)blockIdx.x * 8 + s) * RPG;
    if (start >= n) return;
    long long end = start + RPG;
    if (end > n) end = n;
    int curg = batch[start];
    float a = 0.f, c = 0.f;
    for (long long r = start; r < end; ++r) {
        int g = batch[r];
        if (g != curg) {
            atomicAdd(&sums[(size_t)curg * D + j], a);
            if (j == 0) atomicAdd(&cnt[curg], c);
            a = 0.f; c = 0.f; curg = g;
        }
        a += fabsf(__half2float(x1[(size_t)r * D + j]));
        c += 1.f;
    }
    atomicAdd(&sums[(size_t)curg * D + j], a);
    if (j == 0) atomicAdd(&cnt[curg], c);
}

// ---------- head ----------
__global__ void head_kernel(const float* __restrict__ sums, const float* __restrict__ cnt,
                            const float* __restrict__ w1, const float* __restrict__ b1,
                            const float* __restrict__ w2, const float* __restrict__ b2,
                            float* __restrict__ out) {
    __shared__ float W1s[D * D], W2s[D * 10], B1s[D], B2s[10];
    int tid = threadIdx.x;
    for (int i = tid; i < D * D; i += blockDim.x) W1s[i] = w1[i];
    for (int i = tid; i < D * 10; i += blockDim.x) W2s[i] = w2[i];
    if (tid < D) B1s[tid] = b1[tid];
    if (tid < 10) B2s[tid] = b2[tid];
    __syncthreads();
    int g = tid;
    if (g >= NGC) return;
    float invc = 1.f / fmaxf(cnt[g], 1.f);
    float p[D];
#pragma unroll
    for (int k = 0; k < D; ++k) p[k] = sums[(size_t)g * D + k] * invc;
    float h[D];
#pragma unroll
    for (int j = 0; j < D; ++j) {
        float s = B1s[j];
#pragma unroll
        for (int k = 0; k < D; ++k) s = fmaf(p[k], W1s[k * D + j], s);
        h[j] = fmaxf(s, 0.f);
    }
    float l[10];
    float m = -1e30f;
#pragma unroll
    for (int o = 0; o < 10; ++o) {
        float s = B2s[o];
#pragma unroll
        for (int k = 0; k < D; ++k) s = fmaf(h[k], W2s[k * 10 + o], s);
        l[o] = s;
        m = fmaxf(m, s);
    }
    float den = 0.f;
#pragma unroll
    for (int o = 0; o < 10; ++o) { l[o] = expf(l[o] - m); den += l[o]; }
    float inv = 1.f / den;
#pragma unroll
    for (int o = 0; o < 10; ++o) out[g * 10 + o] = l[o] * inv;
}

extern "C" void kernel_launch(void* const* d_in, const int* in_sizes, int n_in,
                              void* d_out, int out_size, void* d_ws, size_t ws_size,
                              hipStream_t stream) {
    const float* X0 = (const float*)d_in[0];
    const float* X1 = (const float*)d_in[1];
    const float* X2 = (const float*)d_in[2];
    // mats: 0=L0,1=L1,2=L2,3=B2D3,4=D2B1TD1inv,5=D1invB1,6=B2TD2inv
    const int* spr[7]; const int* spc[7]; const float* spv[7]; int spn[7];
    for (int m = 0; m < 7; ++m) {
        spr[m] = (const int*)d_in[3 + m * 3];
        spc[m] = (const int*)d_in[4 + m * 3];
        spv[m] = (const float*)d_in[5 + m * 3];
        spn[m] = in_sizes[3 + m * 3];
    }
    const int* batch1 = (const int*)d_in[24];
    const float* W1 = (const float*)d_in[25];
    const float* W234 = (const float*)d_in[26];
    const float* mlp1_w = (const float*)d_in[27];
    const float* mlp1_b = (const float*)d_in[28];
    const float* mlp2_w = (const float*)d_in[29];
    const float* mlp2_b = (const float*)d_in[30];
    float* out = (float*)d_out;

    const int nrows_mat[7] = { N0C, N1C, N2C, N1C, N1C, N0C, N2C };
    // column base of each mat's source in the concatenated activation buffer
    const int colbase_mat[7] = { RB0, RB1, RB2, RB2, RB0, RB1, RB1 };

    // ---- workspace carve ----
    char* wp = (char*)d_ws;
    __half* Xh64 = (__half*)wp;            wp += (size_t)NRC * 64 * sizeof(__half);
    __half* Ha = (__half*)wp;              wp += (size_t)NRC * 32 * sizeof(__half);
    __half* Hb = (__half*)wp;              wp += (size_t)NRC * 32 * sizeof(__half);
    size_t total_nnz = 0;
    for (int m = 0; m < 7; ++m) total_nnz += (size_t)spn[m];
    int2* cv_base = (int2*)wp;             wp += total_nnz * sizeof(int2);
    size_t total_rp = 0;
    for (int m = 0; m < 7; ++m) total_rp += (size_t)nrows_mat[m] + 1;
    int* rowptr_base = (int*)wp;           wp += total_rp * sizeof(int);
    int* tmp = (int*)wp;                   wp += (size_t)N1C * sizeof(int);
    int* bsums = (int*)wp;                 wp += 1040 * sizeof(int);
    float* sums = (float*)wp;              wp += (size_t)NGC * D * sizeof(float);
    float* cnt = (float*)wp;               wp += (size_t)NGC * sizeof(float);

    int* rp_m[7]; int2* cv_m[7];
    {
        size_t ro = 0, co = 0;
        for (int m = 0; m < 7; ++m) {
            rp_m[m] = rowptr_base + ro;
            cv_m[m] = cv_base + co;
            ro += (size_t)nrows_mat[m] + 1;
            co += (size_t)spn[m];
        }
    }

    // ---- inputs -> fp16 (concatenated [X0;X1;X2], stride 64) ----
    tohalf_kernel<<<2048, 256, 0, stream>>>(X0, Xh64 + (size_t)RB0 * 64, (size_t)N0C * 16);
    tohalf_kernel<<<2048, 256, 0, stream>>>(X1, Xh64 + (size_t)RB1 * 64, (size_t)N1C * 16);
    tohalf_kernel<<<2048, 256, 0, stream>>>(X2, Xh64 + (size_t)RB2 * 64, (size_t)N2C * 16);

    // ---- build CSR (7 mats, reused by all 4 layers) ----
    for (int m = 0; m < 7; ++m) {
        int nr = nrows_mat[m];
        int nnz = spn[m];
        int nb = (nr + SCAN_TILE - 1) / SCAN_TILE;
        hipMemsetAsync(tmp, 0, (size_t)nr * sizeof(int), stream);
        hist_kernel<<<(nnz + 255) / 256, 256, 0, stream>>>(spr[m], tmp, nnz);
        scan_phase1<<<nb, 256, 0, stream>>>(tmp, bsums, nr);
        scan_phase2<<<1, 256, 0, stream>>>(bsums, nb);
        scan_phase3<<<nb, 256, 0, stream>>>(tmp, bsums, rp_m[m], nr);
        set_total_kernel<<<1, 1, 0, stream>>>(rp_m[m] + nr, bsums + nb);
        hipMemcpyAsync(tmp, rp_m[m], (size_t)nr * sizeof(int),
                       hipMemcpyDeviceToDevice, stream);
        scatter_kernel<<<(nnz + 255) / 256, 256, 0, stream>>>(
            spr[m], spc[m], spv[m], tmp, cv_m[m], nnz, colbase_mat[m]);
    }

    // ---- 4 layers ----
    __half* cur = Ha;
    __half* nxt = Hb;
    for (int l = 0; l < 4; ++l) {
        const __half* xact = (l == 0) ? Xh64 : cur;
        __half* dst = (l == 0) ? Ha : nxt;
        const float* Wl = (l == 0) ? W1 : W234 + (size_t)(l - 1) * 7 * 32 * 32;
        const size_t wst = (l == 0) ? (size_t)64 * 32 : (size_t)32 * 32;
#define WPK(k) (Wl + (size_t)(k) * wst)
        int g0 = (int)(((size_t)N0C * 32 + 255) / 256);
        int g1 = (int)(((size_t)N1C * 32 + 255) / 256);
        int g2 = (int)(((size_t)N2C * 32 + 255) / 256);
        if (l == 0) {
            rank_kernel<64, 2><<<g0, 256, 0, stream>>>(
                rp_m[0], cv_m[0], WPK(0), rp_m[5], cv_m[5], WPK(3),
                nullptr, nullptr, nullptr, xact, dst, RB0, 0.5f, N0C);
            rank_kernel<64, 3><<<g1, 256, 0, stream>>>(
                rp_m[4], cv_m[4], WPK(1), rp_m[1], cv_m[1], WPK(2),
                rp_m[3], cv_m[3], WPK(5), xact, dst, RB1, 1.f / 3.f, N1C);
            rank_kernel<64, 2><<<g2, 256, 0, stream>>>(
                rp_m[6], cv_m[6], WPK(4), rp_m[2], cv_m[2], WPK(6),
                nullptr, nullptr, nullptr, xact, dst, RB2, 0.5f, N2C);
            cur = Ha; nxt = Hb;
        } else {
            rank_kernel<32, 2><<<g0, 256, 0, stream>>>(
                rp_m[0], cv_m[0], WPK(0), rp_m[5], cv_m[5], WPK(3),
                nullptr, nullptr, nullptr, xact, dst, RB0, 0.5f, N0C);
            rank_kernel<32, 3><<<g1, 256, 0, stream>>>(
                rp_m[4], cv_m[4], WPK(1), rp_m[1], cv_m[1], WPK(2),
                rp_m[3], cv_m[3], WPK(5), xact, dst, RB1, 1.f / 3.f, N1C);
            rank_kernel<32, 2><<<g2, 256, 0, stream>>>(
                rp_m[6], cv_m[6], WPK(4), rp_m[2], cv_m[2], WPK(6),
                nullptr, nullptr, nullptr, xact, dst, RB2, 0.5f, N2C);
            __half* t2 = cur; cur = nxt; nxt = t2;
        }
#undef WPK
    }

    hipMemsetAsync(sums, 0, (size_t)(NGC * D + NGC) * sizeof(float), stream);
    {
        int groups = (N1C + 511) / 512;
        int blocks = (groups + 7) / 8;
        pool_kernel<<<blocks, 256, 0, stream>>>(cur + (size_t)RB1 * 32, batch1, sums, cnt, N1C);
    }
    head_kernel<<<1, 128, 0, stream>>>(sums, cnt, mlp1_w, mlp1_b, mlp2_w, mlp2_b, out);
}